// Round 11
// baseline (85.935 us; speedup 1.0000x reference)
//
#include <hip/hip_runtime.h>
#include <math.h>

#define N_SAMPLES 524288
#define A_ACT 8
#define D_DIM 64
#define E_DIM 32
#define LOG2PI_F 1.8378770664093453f

#define SORT_THREADS 256
#define CHUNK 512
#define NBLK (N_SAMPLES / CHUNK)      // 1024
#define HIST_SIZE (A_ACT * NBLK)      // 8192
#define SCAN_PER (HIST_SIZE / 256)    // 32

#define TILE_ROWS 128
#define MAIN_THREADS 256
#define NB (N_SAMPLES / TILE_ROWS)    // 4096

typedef __attribute__((ext_vector_type(8))) short bf16x8;
typedef __attribute__((ext_vector_type(4))) float f32x4;

__device__ __forceinline__ short f2bf(float f) {
  unsigned u = __float_as_uint(f);
  unsigned r = (u + 0x7FFFu + ((u >> 16) & 1u)) >> 16;
  return (short)r;
}

// ---------------- Kernel 0: W -> bf16, transposed [a][e][k] ----------------
__global__ __launch_bounds__(256) void wprep_kernel(
    const float* __restrict__ W, short* __restrict__ Wt) {
  int i = blockIdx.x * 256 + threadIdx.x;   // 16384 elements
  int a = i >> 11;
  int e = (i >> 6) & 31;
  int k = i & 63;
  Wt[i] = f2bf(W[a * (D_DIM * E_DIM) + k * E_DIM + e]);
}

// ---------------- Kernel 1: per-chunk histogram ----------------
__global__ __launch_bounds__(SORT_THREADS) void hist_kernel(
    const int* __restrict__ idx, int* __restrict__ hist) {
  __shared__ int cnt[A_ACT];
  int t = threadIdx.x;
  if (t < A_ACT) cnt[t] = 0;
  __syncthreads();
  int base = blockIdx.x * CHUNK;
#pragma unroll
  for (int j = 0; j < CHUNK / SORT_THREADS; ++j) {
    atomicAdd(&cnt[idx[base + j * SORT_THREADS + t]], 1);
  }
  __syncthreads();
  if (t < A_ACT) hist[t * NBLK + blockIdx.x] = cnt[t];
}

// ---------------- Kernel 2: exclusive scan of hist (1 block) ----------------
__global__ __launch_bounds__(256) void scan_kernel(int* __restrict__ hist) {
  __shared__ int sums[256];
  int t = threadIdx.x;
  int vals[SCAN_PER];
  int s = 0;
#pragma unroll
  for (int k = 0; k < SCAN_PER; ++k) {
    vals[k] = hist[t * SCAN_PER + k];
    s += vals[k];
  }
  sums[t] = s;
  __syncthreads();
  for (int off = 1; off < 256; off <<= 1) {
    int v = (t >= off) ? sums[t - off] : 0;
    __syncthreads();
    sums[t] += v;
    __syncthreads();
  }
  int prefix = (t == 0) ? 0 : sums[t - 1];
#pragma unroll
  for (int k = 0; k < SCAN_PER; ++k) {
    int v = vals[k];
    hist[t * SCAN_PER + k] = prefix;
    prefix += v;
  }
}

// ---------------- Kernel 3: stable scatter (builds inv only) ----------------
__global__ __launch_bounds__(SORT_THREADS) void scatter_kernel(
    const int* __restrict__ idx, const int* __restrict__ offs,
    int* __restrict__ inv) {
  __shared__ int base[A_ACT];
  __shared__ int wcnt[4][A_ACT];
  int t = threadIdx.x;
  int wave = t >> 6;
  int lane = t & 63;
  if (t < A_ACT) base[t] = offs[t * NBLK + blockIdx.x];
  __syncthreads();
  int cstart = blockIdx.x * CHUNK;
#pragma unroll
  for (int pass = 0; pass < CHUNK / SORT_THREADS; ++pass) {   // 2 passes
    int i = cstart + pass * SORT_THREADS + t;
    int a = idx[i];
    unsigned long long mymask = 0ULL;
#pragma unroll
    for (int aa = 0; aa < A_ACT; ++aa) {
      unsigned long long m = __ballot(a == aa);
      if (aa == a) mymask = m;
      if (lane == 0) wcnt[wave][aa] = __popcll(m);
    }
    unsigned long long below = (1ULL << lane) - 1ULL;
    int inwave = __popcll(mymask & below);
    __syncthreads();
    int wprefix = 0;
#pragma unroll
    for (int w = 0; w < 4; ++w)
      if (w < wave) wprefix += wcnt[w][a];
    inv[i] = base[a] + wprefix + inwave;
    __syncthreads();
    if (t < A_ACT) {
      int tot = 0;
#pragma unroll
      for (int w = 0; w < 4; ++w) tot += wcnt[w][t];
      base[t] += tot;
    }
    __syncthreads();
  }
}

// ---------------- Kernel 4: streaming-state local-sort MFMA ----------------
// Block = 128 CONSECUTIVE original rows (state read is pure streaming).
// Row m: sorted pos k=inv[m]; uses eps[k]; dest = inv[k] (both run-coalesced
// because stable sort makes inv contiguous per block-actor group).
// Only remaining random traffic: the out scatter.
__global__ __launch_bounds__(MAIN_THREADS, 4) void main_kernel(
    const float* __restrict__ state, const short* __restrict__ Wt,
    const float* __restrict__ bias, const float* __restrict__ lstd,
    const float* __restrict__ eps, const int* __restrict__ idx,
    const int* __restrict__ inv,
    float* __restrict__ out_action, float* __restrict__ out_lp) {
  __shared__ short sA[TILE_ROWS * D_DIM];   // 16 KB bf16 state, orig order
  __shared__ float sE[TILE_ROWS * E_DIM];   // 16 KB eps->action, slot order
  __shared__ float s_lp[TILE_ROWS];         // lp by slot
  __shared__ int s_p[TILE_ROWS];            // slot -> local orig row
  __shared__ int s_ge[TILE_ROWS];           // slot -> global sorted row
  __shared__ int s_dst[TILE_ROWS];          // slot -> out row
  __shared__ int s_wc[2][A_ACT];

  int t = threadIdx.x;
  int g0 = blockIdx.x * TILE_ROWS;
  int w = t >> 6;
  int l = t & 63;

  // Phase 0 (waves 0,1): ballot histogram; keep (a, inwave, inv) in regs.
  int my_a = 0, my_inwave = 0, my_inv = 0;
  if (w < 2) {
    my_a = idx[g0 + t];
    my_inv = inv[g0 + t];
#pragma unroll
    for (int aa = 0; aa < A_ACT; ++aa) {
      unsigned long long m = __ballot(my_a == aa);
      if (aa == my_a) my_inwave = __popcll(m & ((1ULL << l) - 1ULL));
      if (l == 0) s_wc[w][aa] = __popcll(m);
    }
  }

  // Phase 1 (all): stage state coalesced, orig order, bf16, chunk-swizzled.
  {
    int u = t >> 4;          // row-slot 0..15
    int x = t & 15;          // float4 chunk 0..15
#pragma unroll
    for (int it = 0; it < TILE_ROWS / 16; ++it) {
      int row = it * 16 + u;
      float4 v = *(const float4*)(state + (size_t)(g0 + row) * D_DIM + x * 4);
      unsigned lo = ((unsigned)(unsigned short)f2bf(v.y) << 16) |
                    (unsigned)(unsigned short)f2bf(v.x);
      unsigned hi = ((unsigned)(unsigned short)f2bf(v.w) << 16) |
                    (unsigned)(unsigned short)f2bf(v.z);
      int soff = row * D_DIM + (((x >> 1) ^ (row & 7)) << 3) + ((x & 1) << 2);
      *(uint2*)(&sA[soff]) = make_uint2(lo, hi);
    }
  }
  __syncthreads();   // s_wc ready

  // Phase 2 (t<128): slot assignment.
  if (w < 2) {
    int rb = 0;
#pragma unroll
    for (int aa = 0; aa < A_ACT; ++aa) {
      int cnt = s_wc[0][aa] + s_wc[1][aa];
      if (aa < my_a) rb += cnt;
    }
    int rank = my_inwave + (w ? s_wc[0][my_a] : 0);
    int pos = rb + rank;
    s_p[pos] = t;
    s_ge[pos] = my_inv;
  }
  __syncthreads();   // s_p, s_ge ready

  // Phase 2b (t<128): dest gather (run-coalesced: s_ge is 8 contiguous runs).
  if (t < TILE_ROWS) s_dst[t] = inv[s_ge[t]];

  // Phase 3 (all): stage eps by slot (8 contiguous runs -> near-coalesced).
  {
#pragma unroll
    for (int it = 0; it < 4; ++it) {
      int slot = it * 32 + (t >> 3);
      int c = t & 7;
      int grow = s_ge[slot];
      float4 v = *(const float4*)(eps + (size_t)grow * E_DIM + c * 4);
      *(float4*)(&sE[slot * E_DIM + ((c ^ (slot & 7)) << 2)]) = v;
    }
  }
  __syncthreads();

  // Phase 4: per-actor MFMA tiles (padded to 16 rows) + epilogue into LDS.
  int T = 0;
#pragma unroll
  for (int aa = 0; aa < A_ACT; ++aa)
    T += (s_wc[0][aa] + s_wc[1][aa] + 15) >> 4;

  int lrow = l & 15;
  int lk = l >> 4;

  for (int ti = w; ti < T; ti += 4) {
    int a = -1, segs = 0, sege = 0;
    int acc_t = 0, rb = 0;
#pragma unroll
    for (int aa = 0; aa < A_ACT; ++aa) {
      int cnt = s_wc[0][aa] + s_wc[1][aa];
      int nt = (cnt + 15) >> 4;
      if (a < 0 && ti < acc_t + nt) {
        a = aa;
        segs = rb + (ti - acc_t) * 16;
        sege = min(rb + cnt, segs + 16);
      }
      acc_t += nt;
      rb += cnt;
    }

    int apos = min(segs + lrow, sege - 1);
    int arow = s_p[apos];
    f32x4 acc0 = {0.f, 0.f, 0.f, 0.f};
    f32x4 acc1 = {0.f, 0.f, 0.f, 0.f};
#pragma unroll
    for (int ks = 0; ks < 2; ++ks) {
      int kc = ks * 4 + lk;
      bf16x8 aF = *(const bf16x8*)(&sA[arow * D_DIM + ((kc ^ (arow & 7)) << 3)]);
      bf16x8 bF0 = *(const bf16x8*)(Wt + a * (D_DIM * E_DIM) + lrow * D_DIM + kc * 8);
      bf16x8 bF1 = *(const bf16x8*)(Wt + a * (D_DIM * E_DIM) + (16 + lrow) * D_DIM + kc * 8);
      acc0 = __builtin_amdgcn_mfma_f32_16x16x32_bf16(aF, bF0, acc0, 0, 0, 0);
      acc1 = __builtin_amdgcn_mfma_f32_16x16x32_bf16(aF, bF1, acc1, 0, 0, 0);
    }

    float bc0 = bias[a * E_DIM + lrow];
    float bc1 = bias[a * E_DIM + 16 + lrow];
    float ls0 = lstd[a * E_DIM + lrow];
    float ls1 = lstd[a * E_DIM + 16 + lrow];
    float sd0 = expf(ls0), sd1 = expf(ls1);

#pragma unroll
    for (int r = 0; r < 4; ++r) {
      int pos = segs + lk * 4 + r;
      bool valid = (pos < sege);
      int pc = valid ? pos : segs;
      int c1 = 16 + lrow;
      int ad0 = pc * E_DIM + (((lrow >> 2) ^ (pc & 7)) << 2) + (lrow & 3);
      int ad1 = pc * E_DIM + (((c1 >> 2) ^ (pc & 7)) << 2) + (c1 & 3);
      float e0 = sE[ad0], e1 = sE[ad1];
      float act0 = fmaf(sd0, e0, acc0[r] + bc0);
      float act1 = fmaf(sd1, e1, acc1[r] + bc1);
      float lpp = fmaf(-0.5f * e0, e0, -ls0) + fmaf(-0.5f * e1, e1, -ls1);
      if (valid) { sE[ad0] = act0; sE[ad1] = act1; }
      lpp += __shfl_xor(lpp, 1, 64);
      lpp += __shfl_xor(lpp, 2, 64);
      lpp += __shfl_xor(lpp, 4, 64);
      lpp += __shfl_xor(lpp, 8, 64);
      if (valid && lrow == 0) s_lp[pc] = lpp - 16.0f * LOG2PI_F;
    }
  }
  __syncthreads();

  // Phase 5: scatter writeout (the only random traffic left).
#pragma unroll
  for (int it = 0; it < 4; ++it) {
    int slot = it * 32 + (t >> 3);
    int c = t & 7;
    int dest = s_dst[slot];
    float4 v = *(const float4*)(&sE[slot * E_DIM + ((c ^ (slot & 7)) << 2)]);
    *(float4*)(&out_action[(size_t)dest * E_DIM + c * 4]) = v;
  }
  if (t < TILE_ROWS) out_lp[s_dst[t]] = s_lp[t];
}

extern "C" void kernel_launch(void* const* d_in, const int* in_sizes, int n_in,
                              void* d_out, int out_size, void* d_ws, size_t ws_size,
                              hipStream_t stream) {
  const float* state = (const float*)d_in[0];
  const float* W     = (const float*)d_in[1];
  const float* b     = (const float*)d_in[2];
  const float* ls    = (const float*)d_in[3];
  const float* eps   = (const float*)d_in[4];
  const int*   idx   = (const int*)d_in[5];

  float* out_action = (float*)d_out;                              // [N, E]
  float* out_lp     = (float*)d_out + (size_t)N_SAMPLES * E_DIM;  // [N]

  short* Wt   = (short*)d_ws;                        // 32 KB bf16 [a][e][k]
  int*   hist = (int*)((char*)d_ws + 32768);         // 32 KB
  int*   inv  = (int*)((char*)d_ws + 65536);         // 2 MB

  hipLaunchKernelGGL(wprep_kernel, dim3(64), dim3(256), 0, stream, W, Wt);
  hipLaunchKernelGGL(hist_kernel, dim3(NBLK), dim3(SORT_THREADS), 0, stream,
                     idx, hist);
  hipLaunchKernelGGL(scan_kernel, dim3(1), dim3(256), 0, stream, hist);
  hipLaunchKernelGGL(scatter_kernel, dim3(NBLK), dim3(SORT_THREADS), 0, stream,
                     idx, hist, inv);
  hipLaunchKernelGGL(main_kernel, dim3(NB), dim3(MAIN_THREADS), 0, stream,
                     state, Wt, b, ls, eps, idx, inv, out_action, out_lp);
}

// Round 12
// 62.549 us; speedup vs baseline: 1.3739x; 1.3739x over previous
//
#include <hip/hip_runtime.h>
#include <math.h>

#define N_SAMPLES 524288
#define A_ACT 8
#define D_DIM 64
#define E_DIM 32
#define LOG2PI_F 1.8378770664093453f

#define SORT_THREADS 256
#define CHUNK 512
#define NBLK (N_SAMPLES / CHUNK)      // 1024
#define HIST_SIZE (A_ACT * NBLK)      // 8192
#define SCAN_PER (HIST_SIZE / 256)    // 32

typedef __attribute__((ext_vector_type(8))) short bf16x8;
typedef __attribute__((ext_vector_type(4))) float f32x4;

__device__ __forceinline__ short f2bf(float f) {
  unsigned u = __float_as_uint(f);
  unsigned r = (u + 0x7FFFu + ((u >> 16) & 1u)) >> 16;
  return (short)r;
}

// ---------------- Kernel 1: per-chunk histogram (int4-vectorized) ---------
__global__ __launch_bounds__(SORT_THREADS) void hist_kernel(
    const int* __restrict__ idx, int* __restrict__ hist) {
  __shared__ int cnt[A_ACT];
  int t = threadIdx.x;
  if (t < A_ACT) cnt[t] = 0;
  __syncthreads();
  if (t < CHUNK / 4) {
    int4 v = *(const int4*)(idx + blockIdx.x * CHUNK + t * 4);
    atomicAdd(&cnt[v.x], 1);
    atomicAdd(&cnt[v.y], 1);
    atomicAdd(&cnt[v.z], 1);
    atomicAdd(&cnt[v.w], 1);
  }
  __syncthreads();
  if (t < A_ACT) hist[t * NBLK + blockIdx.x] = cnt[t];
}

// ---------------- Kernel 2: exclusive scan of hist (1 block) ----------------
__global__ __launch_bounds__(256) void scan_kernel(int* __restrict__ hist) {
  __shared__ int sums[256];
  int t = threadIdx.x;
  int vals[SCAN_PER];
  int s = 0;
#pragma unroll
  for (int k = 0; k < SCAN_PER; ++k) {
    vals[k] = hist[t * SCAN_PER + k];
    s += vals[k];
  }
  sums[t] = s;
  __syncthreads();
  for (int off = 1; off < 256; off <<= 1) {
    int v = (t >= off) ? sums[t - off] : 0;
    __syncthreads();
    sums[t] += v;
    __syncthreads();
  }
  int prefix = (t == 0) ? 0 : sums[t - 1];
#pragma unroll
  for (int k = 0; k < SCAN_PER; ++k) {
    int v = vals[k];
    hist[t * SCAN_PER + k] = prefix;
    prefix += v;
  }
}

// ---------------- Kernel 3: stable scatter (builds p and inv) ----------------
__global__ __launch_bounds__(SORT_THREADS) void scatter_kernel(
    const int* __restrict__ idx, const int* __restrict__ offs,
    int* __restrict__ p, int* __restrict__ inv) {
  __shared__ int base[A_ACT];
  __shared__ int wcnt[4][A_ACT];
  int t = threadIdx.x;
  int wave = t >> 6;
  int lane = t & 63;
  if (t < A_ACT) base[t] = offs[t * NBLK + blockIdx.x];
  __syncthreads();
  int cstart = blockIdx.x * CHUNK;
#pragma unroll
  for (int pass = 0; pass < CHUNK / SORT_THREADS; ++pass) {   // 2 passes
    int i = cstart + pass * SORT_THREADS + t;
    int a = idx[i];
    unsigned long long mymask = 0ULL;
#pragma unroll
    for (int aa = 0; aa < A_ACT; ++aa) {
      unsigned long long m = __ballot(a == aa);
      if (aa == a) mymask = m;
      if (lane == 0) wcnt[wave][aa] = __popcll(m);
    }
    unsigned long long below = (1ULL << lane) - 1ULL;
    int inwave = __popcll(mymask & below);
    __syncthreads();
    int wprefix = 0;
#pragma unroll
    for (int w = 0; w < 4; ++w)
      if (w < wave) wprefix += wcnt[w][a];
    int r = base[a] + wprefix + inwave;
    p[r] = i;
    inv[i] = r;
    __syncthreads();
    if (t < A_ACT) {
      int tot = 0;
#pragma unroll
      for (int w = 0; w < 4; ++w) tot += wcnt[w][t];
      base[t] += tot;
    }
    __syncthreads();
  }
}

// ---------------- Kernel 4: MFMA matvec + rsample + logprob ----------------
// One actor per block; 256 sorted rows; 512 threads / 8 waves (max gather
// MLP + 32 waves/CU). LDS-staged A (verified swizzle), sB, acc->sC (alias
// sA), vectorized epilogue with prefetched eps/dst.
#define TILE_ROWS 256
#define MAIN_THREADS 512
#define MAIN_BLOCKS (N_SAMPLES / TILE_ROWS + A_ACT)

__global__ __launch_bounds__(MAIN_THREADS, 2) void main_kernel(
    const float* __restrict__ state, const float* __restrict__ W,
    const float* __restrict__ bias, const float* __restrict__ lstd,
    const float* __restrict__ eps, const int* __restrict__ p,
    const int* __restrict__ inv, const int* __restrict__ offs,
    float* __restrict__ out_action, float* __restrict__ out_lp) {
  __shared__ short sA[TILE_ROWS * D_DIM];   // 32 KB bf16; aliased as sC fp32
  __shared__ short sB[E_DIM * D_DIM];       // 4 KB bf16 [col][k], swizzled

  int t = threadIdx.x;
  int bid = blockIdx.x;

  // Map block -> (actor, row chunk): each block serves exactly one actor.
  int a = -1, kbase = 0, kend = 0;
  int acc_b = 0;
#pragma unroll
  for (int aa = 0; aa < A_ACT; ++aa) {
    int start = offs[aa * NBLK];
    int end = (aa == A_ACT - 1) ? N_SAMPLES : offs[(aa + 1) * NBLK];
    int cnt = end - start;
    int nc = (cnt + TILE_ROWS - 1) / TILE_ROWS;
    if (a < 0 && bid < acc_b + nc) {
      a = aa;
      int chunk = bid - acc_b;
      kbase = start + chunk * TILE_ROWS;
      kend = min(end, kbase + TILE_ROWS);
    }
    acc_b += nc;
  }
  if (a < 0) return;  // uniform across block
  int nrows = kend - kbase;

  // Stage B: W[a] fp32 [d=k][e=col] -> sB bf16 [col][k], 16B-chunk swizzle.
  if (t < 256) {
    int col = t >> 3;          // 0..31
    int kc = t & 7;            // k-chunk 0..7 (8 k's each)
    const float* wp = W + (size_t)a * (D_DIM * E_DIM) + (kc * 8) * E_DIM + col;
    bf16x8 v;
#pragma unroll
    for (int j = 0; j < 8; ++j) v[j] = f2bf(wp[j * E_DIM]);
    *(bf16x8*)(&sB[col * D_DIM + ((kc ^ (col & 7)) << 3)]) = v;
  }

  // Stage A: 16 lanes per row (256B coalesced fp32 read) -> bf16, swizzled.
  // Prefetch p[] indices first, then issue all 8 gathers (max MLP).
  {
    int u = t >> 4;            // row-slot 0..31
    int x = t & 15;            // fp32 float4 chunk 0..15
    int pm[TILE_ROWS / 32];
#pragma unroll
    for (int it = 0; it < TILE_ROWS / 32; ++it) {   // 8 iters
      int row = it * 32 + u;
      pm[it] = p[kbase + min(row, nrows - 1)];
    }
#pragma unroll
    for (int it = 0; it < TILE_ROWS / 32; ++it) {
      int row = it * 32 + u;
      float4 v = *(const float4*)(state + (size_t)pm[it] * D_DIM + x * 4);
      unsigned lo = ((unsigned)(unsigned short)f2bf(v.y) << 16) |
                    (unsigned)(unsigned short)f2bf(v.x);
      unsigned hi = ((unsigned)(unsigned short)f2bf(v.w) << 16) |
                    (unsigned)(unsigned short)f2bf(v.z);
      int soff = row * D_DIM + (((x >> 1) ^ (row & 7)) << 3) + ((x & 1) << 2);
      *(uint2*)(&sA[soff]) = make_uint2(lo, hi);
    }
  }

  // Prefetch epilogue data (coalesced; hidden under staging+MFMA latency).
  int c = t & 7;            // col chunk 0..7 (4 cols)
  float4 epv[4];
  int dst[4];
#pragma unroll
  for (int pass = 0; pass < 4; ++pass) {
    int row = pass * 64 + (t >> 3);
    int rc = min(row, nrows - 1);
    epv[pass] = *(const float4*)(eps + (size_t)(kbase + rc) * E_DIM + c * 4);
    dst[pass] = inv[kbase + rc];
  }
  float4 bv = *(const float4*)(bias + a * E_DIM + c * 4);
  float4 lv = *(const float4*)(lstd + a * E_DIM + c * 4);

  __syncthreads();

  int w = t >> 6;      // wave 0..7, owns rows [w*32, w*32+32)
  int l = t & 63;
  int lrow = l & 15;   // A-row / B-col within tile
  int lk = l >> 4;     // k lane-group 0..3
  int r0 = w * 32;

  f32x4 acc[2][2];
#pragma unroll
  for (int rt = 0; rt < 2; ++rt)
#pragma unroll
    for (int ct = 0; ct < 2; ++ct) acc[rt][ct] = (f32x4){0.f, 0.f, 0.f, 0.f};

#pragma unroll
  for (int ks = 0; ks < 2; ++ks) {
    int kc = ks * 4 + lk;
    bf16x8 aF[2], bF[2];
#pragma unroll
    for (int rt = 0; rt < 2; ++rt) {
      int row = r0 + rt * 16 + lrow;
      aF[rt] = *(const bf16x8*)(&sA[row * D_DIM + ((kc ^ (row & 7)) << 3)]);
    }
#pragma unroll
    for (int ct = 0; ct < 2; ++ct) {
      int col = ct * 16 + lrow;
      bF[ct] = *(const bf16x8*)(&sB[col * D_DIM + ((kc ^ (col & 7)) << 3)]);
    }
#pragma unroll
    for (int rt = 0; rt < 2; ++rt)
#pragma unroll
      for (int ct = 0; ct < 2; ++ct)
        acc[rt][ct] = __builtin_amdgcn_mfma_f32_16x16x32_bf16(
            aF[rt], bF[ct], acc[rt][ct], 0, 0, 0);
  }

  __syncthreads();   // all sA reads done; safe to alias as sC

  // Dump acc to LDS. C/D layout: col = lane&15, row = (lane>>4)*4 + reg.
  float* sC = (float*)sA;   // [256 rows][32 cols], 16B-chunk swizzled
#pragma unroll
  for (int rt = 0; rt < 2; ++rt) {
#pragma unroll
    for (int ct = 0; ct < 2; ++ct) {
      int col = ct * 16 + lrow;
#pragma unroll
      for (int r = 0; r < 4; ++r) {
        int row = r0 + rt * 16 + lk * 4 + r;
        sC[row * E_DIM + (((col >> 2) ^ (row & 7)) << 2) + (col & 3)] =
            acc[rt][ct][r];
      }
    }
  }
  __syncthreads();

  // Vectorized epilogue: 8 lanes per row, float4 everywhere.
  const float bva[4] = {bv.x, bv.y, bv.z, bv.w};
  const float lsa[4] = {lv.x, lv.y, lv.z, lv.w};
  float sda[4];
#pragma unroll
  for (int j = 0; j < 4; ++j) sda[j] = expf(lsa[j]);
  float lsum = lsa[0] + lsa[1] + lsa[2] + lsa[3];

#pragma unroll
  for (int pass = 0; pass < 4; ++pass) {
    int row = pass * 64 + (t >> 3);
    bool valid = (row < nrows);
    int rcrow = valid ? row : (nrows - 1);
    float4 av2 = *(const float4*)(&sC[rcrow * E_DIM + ((c ^ (rcrow & 7)) << 2)]);
    const float ep[4] = {epv[pass].x, epv[pass].y, epv[pass].z, epv[pass].w};
    const float ac[4] = {av2.x, av2.y, av2.z, av2.w};
    float o[4];
    float part = -lsum;
#pragma unroll
    for (int j = 0; j < 4; ++j) {
      o[j] = fmaf(sda[j], ep[j], ac[j] + bva[j]);
      part = fmaf(-0.5f * ep[j], ep[j], part);
    }
    part += __shfl_xor(part, 1, 64);
    part += __shfl_xor(part, 2, 64);
    part += __shfl_xor(part, 4, 64);
    if (valid) {
      *(float4*)(&out_action[(size_t)dst[pass] * E_DIM + c * 4]) =
          make_float4(o[0], o[1], o[2], o[3]);
      if (c == 0) out_lp[dst[pass]] = part - 16.0f * LOG2PI_F;
    }
  }
}

extern "C" void kernel_launch(void* const* d_in, const int* in_sizes, int n_in,
                              void* d_out, int out_size, void* d_ws, size_t ws_size,
                              hipStream_t stream) {
  const float* state = (const float*)d_in[0];
  const float* W     = (const float*)d_in[1];
  const float* b     = (const float*)d_in[2];
  const float* ls    = (const float*)d_in[3];
  const float* eps   = (const float*)d_in[4];
  const int*   idx   = (const int*)d_in[5];

  float* out_action = (float*)d_out;                              // [N, E]
  float* out_lp     = (float*)d_out + (size_t)N_SAMPLES * E_DIM;  // [N]

  int* p    = (int*)d_ws;
  int* inv  = p + N_SAMPLES;
  int* hist = inv + N_SAMPLES;

  hipLaunchKernelGGL(hist_kernel, dim3(NBLK), dim3(SORT_THREADS), 0, stream,
                     idx, hist);
  hipLaunchKernelGGL(scan_kernel, dim3(1), dim3(256), 0, stream, hist);
  hipLaunchKernelGGL(scatter_kernel, dim3(NBLK), dim3(SORT_THREADS), 0, stream,
                     idx, hist, p, inv);
  hipLaunchKernelGGL(main_kernel, dim3(MAIN_BLOCKS), dim3(MAIN_THREADS),
                     0, stream, state, W, b, ls, eps, p, inv, hist,
                     out_action, out_lp);
}